// Round 22
// baseline (57.756 us; speedup 1.0000x reference)
//
#include <hip/hip_runtime.h>

#define DD 256
#define BB 64
#define SS 256                       // H*W
#define K2 2.8853900817779268f      // 2*log2(e)
#define LOG2E 1.4426950408889634f

#if __has_builtin(__builtin_amdgcn_exp2f)
#define EXP2(x) __builtin_amdgcn_exp2f(x)
#else
#define EXP2(x) exp2f(x)
#endif

typedef __attribute__((ext_vector_type(8))) short bf16x8;
typedef __attribute__((ext_vector_type(4))) float f32x4;

static __device__ __forceinline__ float fast_rcp(float x) {
  return __builtin_amdgcn_rcpf(x);
}

// ---- kernel 1: blocks 0..7 convert wv_w -> bf16 hi/lo in MFMA-B order;
//      blocks 8..8+T: att_r = pe@wo^T + b ----
// whi/wlo layout: (cc*1024 + dt16*64 + kg*16 + dcol)*8 + j
//   == bf16 parts of wv_w[dt16*16+dcol][cc*32+kg*8+j]
__global__ __launch_bounds__(256) void k_prep(
    const float* __restrict__ wv_w,
    const float* __restrict__ wo_w, const float* __restrict__ wo_b,
    unsigned short* __restrict__ whi, unsigned short* __restrict__ wlo,
    float* __restrict__ att_r, int T)
{
  const int tid = threadIdx.x;
  if (blockIdx.x < 8) {
    const int cc = blockIdx.x;
#pragma unroll
    for (int sl = 0; sl < 4; ++sl) {
      const int slot = sl * 256 + tid;     // 0..1023
      const int dt16 = slot >> 6;          // 0..15
      const int kg   = (slot >> 4) & 3;
      const int dcol = slot & 15;
      const int d  = dt16 * 16 + dcol;
      const int c0 = cc * 32 + kg * 8;
      float4 a = *reinterpret_cast<const float4*>(wv_w + (size_t)d * DD + c0);
      float4 b4 = *reinterpret_cast<const float4*>(wv_w + (size_t)d * DD + c0 + 4);
      const float wf[8] = {a.x, a.y, a.z, a.w, b4.x, b4.y, b4.z, b4.w};
      unsigned hp[4], lp[4];
#pragma unroll
      for (int p = 0; p < 4; ++p) {
        float fa = wf[p * 2], fb = wf[p * 2 + 1];
        unsigned ua = __float_as_uint(fa), ub = __float_as_uint(fb);
        hp[p] = (ua >> 16) | (ub & 0xffff0000u);
        float la = fa - __uint_as_float(ua & 0xffff0000u);
        float lb = fb - __uint_as_float(ub & 0xffff0000u);
        lp[p] = (__float_as_uint(la) >> 16) | (__float_as_uint(lb) & 0xffff0000u);
      }
      const size_t base = ((size_t)cc * 1024 + slot) * 8;
      *reinterpret_cast<uint4*>(whi + base) = make_uint4(hp[0], hp[1], hp[2], hp[3]);
      *reinterpret_cast<uint4*>(wlo + base) = make_uint4(lp[0], lp[1], lp[2], lp[3]);
    }
    return;
  }
  // ---- att_r branch ----
  const int t = blockIdx.x - 8;
  if (t >= T) return;
  __shared__ float pe[DD];
  {
    int i = tid >> 1;
    double r = pow(10000.0, -(double)(2*i) / 256.0);
    double ang = (double)t * r;
    pe[tid] = (float)((tid & 1) ? cos(ang) : sin(ang));
  }
  __syncthreads();
  const float4* wr = reinterpret_cast<const float4*>(wo_w + (size_t)tid * DD);
  const float4* pp = reinterpret_cast<const float4*>(pe);
  float acc = 0.f;
#pragma unroll 8
  for (int k = 0; k < 64; ++k) {
    float4 w4 = wr[k]; float4 p4 = pp[k];
    acc = fmaf(w4.x, p4.x, acc);
    acc = fmaf(w4.y, p4.y, acc);
    acc = fmaf(w4.z, p4.z, acc);
    acc = fmaf(w4.w, p4.w, acc);
  }
  att_r[(size_t)t*DD + tid] = acc + wo_b[tid];
}

// ---- kernel 2 (MFMA, zero-LDS, zero-barrier): att_x = x^T @ wv_w^T + b ----
// grid (4 sT, 4 dQ, 64 b) = 1024 blocks (4/CU, 16 waves/CU), block 256 (4 waves).
// Wave wid: s-rows wid*16..+15; d-quarter dq: d = dq*64 + dtl*16 + dcol (dtl 0..3).
// A: 8 direct global x loads/chunk (lane's s fixed), in-reg bf16 hi/lo split.
// B: whi/wlo b128 loads, lane-consecutive (precomputed MFMA order, L2-resident).
__global__ __launch_bounds__(256) void k_attx(
    const float* __restrict__ x,
    const unsigned short* __restrict__ whi, const unsigned short* __restrict__ wlo,
    const float* __restrict__ wv_b, float* __restrict__ att_x)
{
  const int b   = blockIdx.z;
  const int dq  = blockIdx.y;          // 0..3 -> d-quarter
  const int s0  = blockIdx.x * 64;
  const int tid = threadIdx.x;
  const int lane = tid & 63;
  const int wid  = tid >> 6;
  const int g    = lane >> 4;          // k-group 0..3
  const int scol = lane & 15;
  const float* xcol = x + (size_t)b * DD * SS + s0 + wid * 16 + scol;  // x[c][sA], stride SS

  f32x4 acc[4];
#pragma unroll
  for (int dtl = 0; dtl < 4; ++dtl) acc[dtl] = (f32x4){0.f, 0.f, 0.f, 0.f};

#pragma unroll
  for (int cc = 0; cc < 8; ++cc) {
    // ---- A frags: x[cc*32 + g*8 + j][sA], split hi/lo in-register ----
    union { bf16x8 v; unsigned short u[8]; } ah, al;
#pragma unroll
    for (int j = 0; j < 8; ++j) {
      float f = xcol[(size_t)(cc * 32 + g * 8 + j) * SS];
      unsigned u = __float_as_uint(f);
      ah.u[j] = (unsigned short)(u >> 16);
      float fl = f - __uint_as_float(u & 0xffff0000u);
      al.u[j] = (unsigned short)(__float_as_uint(fl) >> 16);
    }
    // ---- B frags + MFMA (lane-consecutive 16B loads) ----
#pragma unroll
    for (int dtl = 0; dtl < 4; ++dtl) {
      const size_t base = ((size_t)cc * 1024 + (size_t)(dq * 4 + dtl) * 64 + lane) * 8;
      bf16x8 bh = *reinterpret_cast<const bf16x8*>(whi + base);
      bf16x8 bl = *reinterpret_cast<const bf16x8*>(wlo + base);
      acc[dtl] = __builtin_amdgcn_mfma_f32_16x16x32_bf16(ah.v, bh, acc[dtl], 0, 0, 0);
      acc[dtl] = __builtin_amdgcn_mfma_f32_16x16x32_bf16(ah.v, bl, acc[dtl], 0, 0, 0);
      acc[dtl] = __builtin_amdgcn_mfma_f32_16x16x32_bf16(al.v, bh, acc[dtl], 0, 0, 0);
    }
  }

  // ---- epilogue: bias + store.  C/D: col(d)=lane&15, row(s)=(lane>>4)*4+r ----
  const int dcol = lane & 15, rg = lane >> 4;
#pragma unroll
  for (int dtl = 0; dtl < 4; ++dtl) {
    const int d = dq * 64 + dtl * 16 + dcol;
    float bv = wv_b[d];
#pragma unroll
    for (int r = 0; r < 4; ++r) {
      const int s = s0 + wid * 16 + rg * 4 + r;
      att_x[((size_t)(b * SS + s)) * DD + d] = acc[dtl][r] + bv;
    }
  }
}

// ---- kernel 3 (MERGED v6, round-21 verified): scores + softmax + out ----
// grid (64 b, 4 tq), block 1024.  Factored exp: ea(t,d) staged, ef(s,d) in regs.
__global__ __launch_bounds__(1024, 2) void k_score_out(
    const float* __restrict__ att_x, const float* __restrict__ att_r,
    const float* __restrict__ we_w, float* __restrict__ out, int T)
{
  const int b  = blockIdx.x;
  const int tq = blockIdx.y;
  const int tchunk = (T + 3) >> 2;      // <= 8
  const int t0 = tq * tchunk;
  const int nT = (T - t0 < tchunk) ? (T - t0) : tchunk;
  if (nT <= 0) return;
  const int tid = threadIdx.x;

  __shared__ float pool[4096];          // attrS-as-ea (Phase A) / red (Phase B)
  __shared__ float scS[8 * 256];        // scores -> alpha (in place)
  __shared__ float mred[8][4];
  __shared__ float sred[8][4];

  for (int idx = tid; idx < nT * 256; idx += 1024) {
    int tl = idx >> 8, d = idx & 255;
    pool[tl * 320 + (d >> 4) * 20 + (d & 15)] = EXP2(att_r[(size_t)(t0 + tl) * DD + d] * K2);
  }
  for (int idx = tid; idx < 8 * 256; idx += 1024) scS[idx] = 0.f;

  const int sl = tid >> 4;       // 0..63
  const int c  = tid & 15;       // 0..15
  float4 w0, w1, w2, w3;
  {
    const float4* we4 = reinterpret_cast<const float4*>(we_w + c * 16);
    w0 = we4[0]; w1 = we4[1]; w2 = we4[2]; w3 = we4[3];
  }
  __syncthreads();

#pragma unroll
  for (int q = 0; q < 4; ++q) {
    const int s = q * 64 + sl;
    float f0x, f0y, f0z, f0w, f1x, f1y, f1z, f1w;
    float f2x, f2y, f2z, f2w, f3x, f3y, f3z, f3w;
    {
      const float4* ax4 = reinterpret_cast<const float4*>(
          att_x + ((size_t)(b * SS + s)) * DD + c * 16);
      float4 a = ax4[0], bq = ax4[1], cq = ax4[2], dq = ax4[3];
      f0x = EXP2(a.x*K2);  f0y = EXP2(a.y*K2);  f0z = EXP2(a.z*K2);  f0w = EXP2(a.w*K2);
      f1x = EXP2(bq.x*K2); f1y = EXP2(bq.y*K2); f1z = EXP2(bq.z*K2); f1w = EXP2(bq.w*K2);
      f2x = EXP2(cq.x*K2); f2y = EXP2(cq.y*K2); f2z = EXP2(cq.z*K2); f2w = EXP2(cq.w*K2);
      f3x = EXP2(dq.x*K2); f3y = EXP2(dq.y*K2); f3z = EXP2(dq.z*K2); f3w = EXP2(dq.w*K2);
    }
#pragma unroll 2
    for (int tl = 0; tl < nT; ++tl) {
      const float* aS = &pool[tl * 320 + c * 20];
      float4 a0 = *reinterpret_cast<const float4*>(aS);
      float4 a1 = *reinterpret_cast<const float4*>(aS + 4);
      float4 a2 = *reinterpret_cast<const float4*>(aS + 8);
      float4 a3 = *reinterpret_cast<const float4*>(aS + 12);
      float p0 = 0.f, p1 = 0.f, p2 = 0.f, p3 = 0.f;
      p0 = fmaf(w0.x, fast_rcp(fmaf(f0x, a0.x, 1.f)), p0);
      p0 = fmaf(w0.y, fast_rcp(fmaf(f0y, a0.y, 1.f)), p0);
      p0 = fmaf(w0.z, fast_rcp(fmaf(f0z, a0.z, 1.f)), p0);
      p0 = fmaf(w0.w, fast_rcp(fmaf(f0w, a0.w, 1.f)), p0);
      p1 = fmaf(w1.x, fast_rcp(fmaf(f1x, a1.x, 1.f)), p1);
      p1 = fmaf(w1.y, fast_rcp(fmaf(f1y, a1.y, 1.f)), p1);
      p1 = fmaf(w1.z, fast_rcp(fmaf(f1z, a1.z, 1.f)), p1);
      p1 = fmaf(w1.w, fast_rcp(fmaf(f1w, a1.w, 1.f)), p1);
      p2 = fmaf(w2.x, fast_rcp(fmaf(f2x, a2.x, 1.f)), p2);
      p2 = fmaf(w2.y, fast_rcp(fmaf(f2y, a2.y, 1.f)), p2);
      p2 = fmaf(w2.z, fast_rcp(fmaf(f2z, a2.z, 1.f)), p2);
      p2 = fmaf(w2.w, fast_rcp(fmaf(f2w, a2.w, 1.f)), p2);
      p3 = fmaf(w3.x, fast_rcp(fmaf(f3x, a3.x, 1.f)), p3);
      p3 = fmaf(w3.y, fast_rcp(fmaf(f3y, a3.y, 1.f)), p3);
      p3 = fmaf(w3.z, fast_rcp(fmaf(f3z, a3.z, 1.f)), p3);
      p3 = fmaf(w3.w, fast_rcp(fmaf(f3w, a3.w, 1.f)), p3);
      float part = (p0 + p1) + (p2 + p3);
      part += __shfl_xor(part, 1);
      part += __shfl_xor(part, 2);
      part += __shfl_xor(part, 4);
      part += __shfl_xor(part, 8);
      if (c == 0) scS[tl * 256 + s] = -2.f * part;  // + softmax-invariant const (dropped)
    }
  }
  __syncthreads();

  const int d   = tid & 255;
  const int scg = tid >> 8;   // 0..3
  const int wv4 = d >> 6;
#pragma unroll
  for (int pass = 0; pass < 2; ++pass) {
    const int r = pass * 4 + scg;       // 0..7
    const bool live = (r < nT);
    float v = live ? scS[r * 256 + d] : -3.0e38f;
    float m = v;
    m = fmaxf(m, __shfl_xor(m, 1));
    m = fmaxf(m, __shfl_xor(m, 2));
    m = fmaxf(m, __shfl_xor(m, 4));
    m = fmaxf(m, __shfl_xor(m, 8));
    m = fmaxf(m, __shfl_xor(m, 16));
    m = fmaxf(m, __shfl_xor(m, 32));
    if ((tid & 63) == 0) mred[r][wv4] = m;
    __syncthreads();
    float M = fmaxf(fmaxf(mred[r][0], mred[r][1]), fmaxf(mred[r][2], mred[r][3]));
    float ev = live ? EXP2((v - M) * LOG2E) : 0.f;
    float ss = ev;
    ss += __shfl_xor(ss, 1);
    ss += __shfl_xor(ss, 2);
    ss += __shfl_xor(ss, 4);
    ss += __shfl_xor(ss, 8);
    ss += __shfl_xor(ss, 16);
    ss += __shfl_xor(ss, 32);
    if ((tid & 63) == 0) sred[r][wv4] = ss;
    __syncthreads();
    float S = sred[r][0] + sred[r][1] + sred[r][2] + sred[r][3];
    if (live) scS[r * 256 + d] = ev * fast_rcp(S);
  }
  __syncthreads();     // pool-as-ea dead; pool becomes red

  float v[64];
  const float* ax = att_x + ((size_t)(b * SS) + scg * 64) * DD + d;
#pragma unroll
  for (int i = 0; i < 64; ++i) v[i] = ax[(size_t)i * DD];

#pragma unroll
  for (int half = 0; half < 2; ++half) {
    const int nR = (nT - half * 4 < 4) ? (nT - half * 4) : 4;
#pragma unroll
    for (int tl = 0; tl < 4; ++tl) {
      float a = 0.f;
#pragma unroll
      for (int i4 = 0; i4 < 16; ++i4) {
        float4 a4 = *reinterpret_cast<const float4*>(
            &scS[(half * 4 + tl) * 256 + scg * 64 + i4 * 4]);   // wave-uniform
        a = fmaf(a4.x, v[i4*4+0], a);
        a = fmaf(a4.y, v[i4*4+1], a);
        a = fmaf(a4.z, v[i4*4+2], a);
        a = fmaf(a4.w, v[i4*4+3], a);
      }
      pool[scg * 1024 + tl * 256 + d] = a;       // pool-as-red
    }
    __syncthreads();
    for (int idx = tid; idx < nR * 256; idx += 1024) {
      float sum = pool[idx] + pool[1024 + idx] + pool[2048 + idx] + pool[3072 + idx];
      out[((size_t)b * T + t0 + half * 4) * SS + idx] = sum * (1.0f / 256.0f);
    }
    __syncthreads();
  }
}

extern "C" void kernel_launch(void* const* d_in, const int* in_sizes, int n_in,
                              void* d_out, int out_size, void* d_ws, size_t ws_size,
                              hipStream_t stream) {
  (void)in_sizes; (void)n_in; (void)ws_size;
  const float* x    = (const float*)d_in[0];
  // d_in[1] = seq_len (device int scalar) -- T derived from out_size instead
  const float* wo_w = (const float*)d_in[2];
  const float* wo_b = (const float*)d_in[3];
  const float* wv_w = (const float*)d_in[4];
  const float* wv_b = (const float*)d_in[5];
  const float* we_w = (const float*)d_in[6];
  float* out = (float*)d_out;
  const int T = out_size / (BB * DD);

  float* att_x = (float*)d_ws;                           // 64*256*256 floats (16 MB)
  float* att_r = att_x + (size_t)BB * SS * DD;           // T*DD floats (<=8K)
  unsigned short* whi = (unsigned short*)(att_r + 32 * DD);   // 65536 shorts (128 KB)
  unsigned short* wlo = whi + 65536;                          // 65536 shorts (128 KB)

  k_prep      <<<dim3(8 + T), 256, 0, stream>>>(wv_w, wo_w, wo_b, whi, wlo, att_r, T);
  k_attx      <<<dim3(4, 4, BB), 256, 0, stream>>>(x, whi, wlo, wv_b, att_x);
  k_score_out <<<dim3(BB, 4), 1024, 0, stream>>>(att_x, att_r, we_w, out, T);
}